// Round 8
// baseline (417.606 us; speedup 1.0000x reference)
//
#include <hip/hip_runtime.h>

// Problem constants (match reference file)
constexpr int B = 32768;
constexpr int D = 1024;
constexpr int S = 64;
constexpr int O = 4;

constexpr int BLOCKS        = 1024;          // 4 blocks/CU, fully co-resident
constexpr int WAVES         = BLOCKS * 4;    // 4096 waves
constexpr int ROWS_PER_WAVE = B / WAVES;     // 8

// Natural-order streaming kernel. No sort, no perm, no LDS.
//  - wave w processes rows w, w+4096, ... (device sweeps x front-to-back:
//    sequential HBM pages — the R7 diagnostic showed perm-order 4 KiB
//    gathers collapse HBM to 2.4 TB/s vs 6.9 TB/s for sequential).
//  - lane owns d = k*64 + lane: x scalar loads coalesced (256 B/instr),
//    W float4 loads perfectly coalesced (1 KiB/instr), W L2-resident (1 MiB).
//  - 2-deep pipeline: next row's x + sid prefetched under current FMAs;
//    W reloaded immediately after FMAs consume it (L2 ~400 cyc, hidden).
__global__ __launch_bounds__(256, 4) void main_kernel(
    const float* __restrict__ x,      // [B, D]
    const int*   __restrict__ sid,    // [B]
    const float* __restrict__ W,      // [S, D, O]
    const float* __restrict__ bias,   // [S, O]
    float*       __restrict__ out)    // [B, O]
{
    const int lane = threadIdx.x & 63;
    const int wave = __builtin_amdgcn_readfirstlane(threadIdx.x >> 6);
    const int w0   = blockIdx.x * 4 + wave;            // 0..4095, wave-uniform

    const int q = lane >> 4;                           // output this lane finalizes

    // ---- preload row 0 state ----
    int row = w0;
    int s   = sid[row];                                // scalar (row uniform)

    float xs[16];
    {
        const float* __restrict__ xr = x + (size_t)row * D;
        #pragma unroll
        for (int k = 0; k < 16; ++k) xs[k] = xr[k * 64 + lane];
    }
    float4 wv[16];
    {
        const float4* __restrict__ Wr = (const float4*)(W + (size_t)s * (D * O));
        #pragma unroll
        for (int k = 0; k < 16; ++k) wv[k] = Wr[k * 64 + lane];
    }

    #pragma unroll 1
    for (int it = 0; it < ROWS_PER_WAVE; ++it) {
        const bool has_next = (it + 1 < ROWS_PER_WAVE);
        const int  row_next = row + WAVES;

        // early: next sid (scalar) — resolves while FMAs run
        int s_next = 0;
        if (has_next) s_next = sid[row_next];

        // prefetch next row's x (addresses known — no perm dependency)
        float xn[16];
        if (has_next) {
            const float* __restrict__ xrn = x + (size_t)row_next * D;
            #pragma unroll
            for (int k = 0; k < 16; ++k) xn[k] = xrn[k * 64 + lane];
        }

        // ---- compute current row ----
        float a0 = 0.f, a1 = 0.f, a2 = 0.f, a3 = 0.f;
        #pragma unroll
        for (int k = 0; k < 16; ++k) {
            a0 += xs[k] * wv[k].x;
            a1 += xs[k] * wv[k].y;
            a2 += xs[k] * wv[k].z;
            a3 += xs[k] * wv[k].w;
        }

        // W regs now free: issue next row's W loads (L2-hot) before reduction
        if (has_next) {
            const float4* __restrict__ Wrn = (const float4*)(W + (size_t)s_next * (D * O));
            #pragma unroll
            for (int k = 0; k < 16; ++k) wv[k] = Wrn[k * 64 + lane];
        }

        const float bb = bias[s * O + q];

        // 12-op reduction: xor{16,32} on 4 accs -> per-(lane%16) partials;
        // lane picks q = lane>>4; xor{1,2,4,8} sums the 16 residues.
        #pragma unroll
        for (int m = 16; m <= 32; m <<= 1) {
            a0 += __shfl_xor(a0, m, 64);
            a1 += __shfl_xor(a1, m, 64);
            a2 += __shfl_xor(a2, m, 64);
            a3 += __shfl_xor(a3, m, 64);
        }
        float v = (q == 0) ? a0 : (q == 1) ? a1 : (q == 2) ? a2 : a3;
        #pragma unroll
        for (int m = 1; m <= 8; m <<= 1)
            v += __shfl_xor(v, m, 64);

        if ((lane & 15) == 0)                          // lanes 0,16,32,48 -> o=0..3
            out[(size_t)row * O + q] = v + bb;

        // rotate pipeline
        if (has_next) {
            #pragma unroll
            for (int k = 0; k < 16; ++k) xs[k] = xn[k];
            row = row_next;
            s   = s_next;
        }
    }
}

extern "C" void kernel_launch(void* const* d_in, const int* in_sizes, int n_in,
                              void* d_out, int out_size, void* d_ws, size_t ws_size,
                              hipStream_t stream) {
    const float* x    = (const float*)d_in[0];   // [B, D]
    const int*   sid  = (const int*)d_in[1];     // [B]
    const float* W    = (const float*)d_in[2];   // [S, D, O]
    const float* bias = (const float*)d_in[3];   // [S, O]
    float* out = (float*)d_out;                  // [B, O]

    main_kernel<<<BLOCKS, 256, 0, stream>>>(x, sid, W, bias, out);
}

// Round 9
// 203.999 us; speedup vs baseline: 2.0471x; 2.0471x over previous
//
#include <hip/hip_runtime.h>

// Problem constants (match reference file)
constexpr int B = 32768;
constexpr int D = 1024;
constexpr int S = 64;
constexpr int O = 4;

constexpr int BLOCKS        = 2048;           // 8 blocks/CU, all co-resident at 32 waves/CU
constexpr int WAVES_TOTAL   = BLOCKS * 4;     // 8192
constexpr int ROWS_PER_WAVE = B / WAVES_TOTAL; // 4 contiguous rows per wave

// Natural-order streaming, register-budget-aware (R8 spilled: needed ~110
// VGPR, compiler allocated 64 and pushed ~600 MB of scratch through HBM).
// Row split into 4 chunks of 256 elements; lane owns d = c*256 + j*64 + lane.
// Double-buffered chunk pipeline: FMA chunk c while chunk c+1 (or next row's
// chunk 0) is in flight. Live state: 2*(4 x + 4 W-float4) = 40 VGPR + 4 acc
// + addresses ~= 60 VGPR -> fits the compiler's 64-reg / 8-waves-per-EU
// preference with NO spill.
__global__ __launch_bounds__(256) void main_kernel(
    const float* __restrict__ x,      // [B, D]
    const int*   __restrict__ sid,    // [B]
    const float* __restrict__ W,      // [S, D, O]
    const float* __restrict__ bias,   // [S, O]
    float*       __restrict__ out)    // [B, O]
{
    const int lane = threadIdx.x & 63;
    const int wave = threadIdx.x >> 6;
    const int gw   = blockIdx.x * 4 + wave;    // 0..8191, wave-uniform
    const int q    = lane >> 4;                // output index this lane finalizes

    int row = gw * ROWS_PER_WAVE;
    int s   = sid[row];                        // wave-uniform -> scalar load

    const float*  xr = x + (size_t)row * D;
    const float4* Wr = (const float4*)(W + (size_t)s * (D * O));

    float  xb[2][4];
    float4 wb[2][4];

    // Preload chunk 0 of first row.
    #pragma unroll
    for (int j = 0; j < 4; ++j) xb[0][j] = xr[j * 64 + lane];
    #pragma unroll
    for (int j = 0; j < 4; ++j) wb[0][j] = Wr[j * 64 + lane];

    #pragma unroll 1
    for (int it = 0; it < ROWS_PER_WAVE; ++it) {
        const bool has_next = (it + 1 < ROWS_PER_WAVE);
        const int  s_next   = has_next ? sid[row + 1] : 0;   // scalar, early

        float a0 = 0.f, a1 = 0.f, a2 = 0.f, a3 = 0.f;

        #pragma unroll
        for (int c = 0; c < 4; ++c) {
            const int cur = c & 1;
            const int nxt = cur ^ 1;

            // Issue the next chunk's loads before consuming the current one.
            if (c < 3) {
                const int base = (c + 1) * 256;
                #pragma unroll
                for (int j = 0; j < 4; ++j) xb[nxt][j] = xr[base + j * 64 + lane];
                #pragma unroll
                for (int j = 0; j < 4; ++j) wb[nxt][j] = Wr[base / 4 * 4 + j * 64 + lane];
            } else if (has_next) {
                const float*  xrn = x + (size_t)(row + 1) * D;
                const float4* Wrn = (const float4*)(W + (size_t)s_next * (D * O));
                #pragma unroll
                for (int j = 0; j < 4; ++j) xb[nxt][j] = xrn[j * 64 + lane];
                #pragma unroll
                for (int j = 0; j < 4; ++j) wb[nxt][j] = Wrn[j * 64 + lane];
            }

            // FMA current chunk (waits only on its own loads: partial vmcnt).
            #pragma unroll
            for (int j = 0; j < 4; ++j) {
                a0 += xb[cur][j] * wb[cur][j].x;
                a1 += xb[cur][j] * wb[cur][j].y;
                a2 += xb[cur][j] * wb[cur][j].z;
                a3 += xb[cur][j] * wb[cur][j].w;
            }
        }

        const float bb = bias[s * O + q];

        // 12-op reduction: xor{16,32} on 4 accs -> per-(lane%16) partials;
        // lane picks q = lane>>4; xor{1,2,4,8} sums the 16 residues.
        #pragma unroll
        for (int m = 16; m <= 32; m <<= 1) {
            a0 += __shfl_xor(a0, m, 64);
            a1 += __shfl_xor(a1, m, 64);
            a2 += __shfl_xor(a2, m, 64);
            a3 += __shfl_xor(a3, m, 64);
        }
        float v = (q == 0) ? a0 : (q == 1) ? a1 : (q == 2) ? a2 : a3;
        #pragma unroll
        for (int m = 1; m <= 8; m <<= 1)
            v += __shfl_xor(v, m, 64);

        if ((lane & 15) == 0)                  // lanes 0,16,32,48 -> o = 0..3
            out[(size_t)row * O + q] = v + bb;

        // Rotate to next row (its chunk 0 already lands in buffer 0:
        // c=3 loaded into nxt = 0, and the next row's c-loop starts at cur=0).
        row += 1;
        s    = s_next;
        xr   = x + (size_t)row * D;
        Wr   = (const float4*)(W + (size_t)s * (D * O));
    }
}

extern "C" void kernel_launch(void* const* d_in, const int* in_sizes, int n_in,
                              void* d_out, int out_size, void* d_ws, size_t ws_size,
                              hipStream_t stream) {
    const float* x    = (const float*)d_in[0];   // [B, D]
    const int*   sid  = (const int*)d_in[1];     // [B]
    const float* W    = (const float*)d_in[2];   // [S, D, O]
    const float* bias = (const float*)d_in[3];   // [S, O]
    float* out = (float*)d_out;                  // [B, O]

    main_kernel<<<BLOCKS, 256, 0, stream>>>(x, sid, W, bias, out);
}